// Round 2
// baseline (552.000 us; speedup 1.0000x reference)
//
#include <hip/hip_runtime.h>
#include <hip/hip_bf16.h>

#define NB    2
#define NK    2048
#define NPTS  16384
#define NBK   4096            // NB*NK
#define MSAMP 65536.0f        // NBK*16 samples per scale for BN0/BN1
#define MROW  4096.0f         // rows for final BN

// ---------------------------------------------------------------------------
// K1: BEV bilinear interpolation -> feats[:, 0:256]
// ---------------------------------------------------------------------------
__global__ __launch_bounds__(256) void bev_kernel(
    const float* __restrict__ kp, const float* __restrict__ bev,
    const int* __restrict__ stridep, float* __restrict__ feats)
{
  const int bk = blockIdx.x;           // 0..4095
  const int c  = threadIdx.x;          // channel 0..255
  const int b  = bk >> 11;
  const float st = (float)(*stridep);
  const float x = (kp[bk*3+0] - (-70.4f)) / 0.1f / st;
  const float y = (kp[bk*3+1] - (-40.0f)) / 0.1f / st;
  const int xf = (int)floorf(x), yf = (int)floorf(y);
  const int x0 = min(max(xf, 0), 175), x1 = min(max(xf + 1, 0), 175);
  const int y0 = min(max(yf, 0), 99),  y1 = min(max(yf + 1, 0), 99);
  const float x0f = (float)x0, x1f = (float)x1, y0f = (float)y0, y1f = (float)y1;
  const float wa = (x1f - x) * (y1f - y);
  const float wb = (x1f - x) * (y - y0f);
  const float wc = (x - x0f) * (y1f - y);
  const float wd = (x - x0f) * (y - y0f);
  const size_t base = ((size_t)b * 256 + c) * 17600;  // 100*176
  const float Ia = bev[base + y0 * 176 + x0];
  const float Ib = bev[base + y1 * 176 + x0];
  const float Ic = bev[base + y0 * 176 + x1];
  const float Id = bev[base + y1 * 176 + x1];
  feats[(size_t)bk * 304 + c] = Ia * wa + Ib * wb + Ic * wc + Id * wd;
}

// ---------------------------------------------------------------------------
// K2: ball query + grouping. 1 wave per keypoint, 4 waves/block.
// Writes g0,g1 (bk,slot,4) f32, cnt, and per-block BN0 moment partials:
// part0[block][28] = per-scale {Sx(4), Sxx upper-tri(10)} over the 16 slots.
// ---------------------------------------------------------------------------
__global__ __launch_bounds__(256) void group_kernel(
    const float* __restrict__ kp, const float* __restrict__ pts,
    const float* __restrict__ pfeat,
    float* __restrict__ g0buf, float* __restrict__ g1buf,
    int* __restrict__ cnt, float* __restrict__ part0)
{
  __shared__ float slots[4][2][16][4];
  __shared__ float bred[4][28];
  const int wave = threadIdx.x >> 6;
  const int lane = threadIdx.x & 63;
  const int bk = blockIdx.x * 4 + wave;
  const int b  = bk >> 11;
  const float kx = kp[bk*3+0];
  const float ky = kp[bk*3+1];
  const float kz = kp[bk*3+2];
  const float* px = pts   + (size_t)b * NPTS * 3;
  const float* pf = pfeat + (size_t)b * NPTS;
  int c0 = 0, c1 = 0;
  const unsigned long long below = (1ull << lane) - 1ull;

  for (int base = 0; base < NPTS; base += 64) {
    const int j = base + lane;
    const float x = px[j*3+0];
    const float y = px[j*3+1];
    const float z = px[j*3+2];
    const float dx = x - kx, dy = y - ky, dz = z - kz;
    const float d2 = dx*dx + dy*dy + dz*dz;
    const bool w0 = d2 < 0.16f;   // 0.4^2
    const bool w1 = d2 < 0.64f;   // 0.8^2
    const unsigned long long m1 = __ballot(w1);
    if (m1) {                      // rare (~most iterations have no hits)
      const unsigned long long m0 = __ballot(w0);
      const float f = pf[j];
      const int o0 = c0 + __popcll(m0 & below);
      if (w0 && o0 < 16) {
        slots[wave][0][o0][0] = dx; slots[wave][0][o0][1] = dy;
        slots[wave][0][o0][2] = dz; slots[wave][0][o0][3] = f;
      }
      const int o1 = c1 + __popcll(m1 & below);
      if (w1 && o1 < 16) {
        slots[wave][1][o1][0] = dx; slots[wave][1][o1][1] = dy;
        slots[wave][1][o1][2] = dz; slots[wave][1][o1][3] = f;
      }
      c0 += __popcll(m0);
      c1 += __popcll(m1);
      if (c0 >= 16) break;        // c1 >= c0 always (w0 subset of w1)
    }
  }

  // padding: empty -> zeros, partial -> replicate slot 0
  if (lane < 32) {
    const int s  = (lane >> 4) & 1;
    const int sl = lane & 15;
    const int cs = s ? c1 : c0;
    if (cs == 0) {
      slots[wave][s][sl][0] = 0.f; slots[wave][s][sl][1] = 0.f;
      slots[wave][s][sl][2] = 0.f; slots[wave][s][sl][3] = 0.f;
    } else if (sl >= cs) {
      slots[wave][s][sl][0] = slots[wave][s][0][0];
      slots[wave][s][sl][1] = slots[wave][s][0][1];
      slots[wave][s][sl][2] = slots[wave][s][0][2];
      slots[wave][s][sl][3] = slots[wave][s][0][3];
    }
  }

  // write grouped data (64 floats per scale per keypoint, coalesced)
  g0buf[(size_t)bk * 64 + lane] = slots[wave][0][lane >> 2][lane & 3];
  g1buf[(size_t)bk * 64 + lane] = slots[wave][1][lane >> 2][lane & 3];
  if (lane == 0) { cnt[bk] = c0; cnt[NBK + bk] = c1; }

  // BN0 moment partials: lanes 0..15 scale0 slots, lanes 16..31 scale1 slots
  float v[14];
  {
    float x0 = 0.f, x1 = 0.f, x2 = 0.f, x3 = 0.f;
    if (lane < 32) {
      const int s  = (lane >> 4) & 1;
      const int sl = lane & 15;
      x0 = slots[wave][s][sl][0]; x1 = slots[wave][s][sl][1];
      x2 = slots[wave][s][sl][2]; x3 = slots[wave][s][sl][3];
    }
    v[0] = x0; v[1] = x1; v[2] = x2; v[3] = x3;
    v[4] = x0*x0; v[5] = x0*x1; v[6]  = x0*x2; v[7]  = x0*x3;
    v[8] = x1*x1; v[9] = x1*x2; v[10] = x1*x3;
    v[11] = x2*x2; v[12] = x2*x3; v[13] = x3*x3;
  }
  #pragma unroll
  for (int d = 1; d < 16; d <<= 1) {
    #pragma unroll
    for (int i = 0; i < 14; i++) v[i] += __shfl_xor(v[i], d);
  }
  if (lane == 0 || lane == 16) {
    float* dst = &bred[wave][(lane >> 4) * 14];
    #pragma unroll
    for (int i = 0; i < 14; i++) dst[i] = v[i];
  }
  __syncthreads();
  if (threadIdx.x < 28) {
    const int i = threadIdx.x;
    part0[blockIdx.x * 28 + i] = bred[0][i] + bred[1][i] + bred[2][i] + bred[3][i];
  }
}

// ---------------------------------------------------------------------------
// K3: finalize BN0 (both scales) from moment partials.
// params[0:16]=A0s0 [16:32]=B0s0 [32:48]=A0s1 [48:64]=B0s1
// ---------------------------------------------------------------------------
__global__ __launch_bounds__(256) void finalize0_kernel(
    const float* __restrict__ part0,
    const float* __restrict__ W0s0, const float* __restrict__ gm0, const float* __restrict__ bt0,
    const float* __restrict__ W0s1, const float* __restrict__ gm1, const float* __restrict__ bt1,
    float* __restrict__ params)
{
  __shared__ float lred[4][28];
  __shared__ float S[28];
  const int t = threadIdx.x;
  float v[28];
  #pragma unroll
  for (int i = 0; i < 28; i++) v[i] = 0.f;
  for (int r = t; r < 1024; r += 256) {
    const float* p = part0 + r * 28;
    #pragma unroll
    for (int i = 0; i < 28; i++) v[i] += p[i];
  }
  #pragma unroll
  for (int d = 1; d < 64; d <<= 1) {
    #pragma unroll
    for (int i = 0; i < 28; i++) v[i] += __shfl_xor(v[i], d);
  }
  const int wave = t >> 6, lane = t & 63;
  if (lane == 0) {
    for (int i = 0; i < 28; i++) lred[wave][i] = v[i];
  }
  __syncthreads();
  if (t < 28) S[t] = lred[0][t] + lred[1][t] + lred[2][t] + lred[3][t];
  __syncthreads();
  if (t < 32) {
    const int s = t >> 4, c = t & 15;
    const float* W  = s ? W0s1 : W0s0;
    const float* G  = s ? gm1  : gm0;
    const float* Bt = s ? bt1  : bt0;
    const float* Sx = S + s * 14;
    const float w0 = W[c*4+0], w1 = W[c*4+1];
    const float w2 = W[c*4+2], w3 = W[c*4+3];
    const float inv = 1.0f / MSAMP;
    const float mean = (w0*Sx[0] + w1*Sx[1] + w2*Sx[2] + w3*Sx[3]) * inv;
    float e2 = w0*w0*Sx[4] + 2.f*w0*w1*Sx[5] + 2.f*w0*w2*Sx[6] + 2.f*w0*w3*Sx[7]
             + w1*w1*Sx[8] + 2.f*w1*w2*Sx[9] + 2.f*w1*w3*Sx[10]
             + w2*w2*Sx[11] + 2.f*w2*w3*Sx[12] + w3*w3*Sx[13];
    e2 *= inv;
    const float var = e2 - mean * mean;
    const float A = G[c] / sqrtf(var + 1e-5f);
    params[s*32 + c]      = A;
    params[s*32 + 16 + c] = Bt[c] - mean * A;
  }
}

// ---------------------------------------------------------------------------
// K4: second-layer BN stats: sum/sumsq of h2 for both scales.
// part1[block][96]: [0:16]=sum_s0 [16:32]=sq_s0 [32:64]=sum_s1 [64:96]=sq_s1
// ---------------------------------------------------------------------------
__global__ __launch_bounds__(256) void stats1_kernel(
    const float* __restrict__ g0buf, const float* __restrict__ g1buf,
    const float* __restrict__ params,
    const float* __restrict__ W0s0, const float* __restrict__ W0s1,
    const float* __restrict__ W1s0, const float* __restrict__ W1s1,
    float* __restrict__ part1)
{
  __shared__ float sW0a[64], sW0b[64], sW1a[256], sW1b[512], sP[64];
  __shared__ float lred[4][96];
  const int t = threadIdx.x;
  if (t < 64) { sW0a[t] = W0s0[t]; sW0b[t] = W0s1[t]; sP[t] = params[t]; }
  sW1a[t]       = W1s0[t];
  sW1b[t]       = W1s1[t];
  sW1b[t + 256] = W1s1[t + 256];
  __syncthreads();

  float acc[96];
  #pragma unroll
  for (int i = 0; i < 96; i++) acc[i] = 0.f;

  for (int slot = blockIdx.x * 256 + t; slot < 65536; slot += 32 * 256) {
    float a1[16];
    {
      const float4 x = *(const float4*)(g0buf + (size_t)slot * 4);
      #pragma unroll
      for (int c = 0; c < 16; c++) {
        const float h = sW0a[c*4+0]*x.x + sW0a[c*4+1]*x.y + sW0a[c*4+2]*x.z + sW0a[c*4+3]*x.w;
        a1[c] = fmaxf(fmaf(sP[c], h, sP[16+c]), 0.f);
      }
      #pragma unroll
      for (int o = 0; o < 16; o++) {
        float h2 = 0.f;
        #pragma unroll
        for (int c = 0; c < 16; c++) h2 = fmaf(sW1a[o*16+c], a1[c], h2);
        acc[o]    += h2;
        acc[16+o]  = fmaf(h2, h2, acc[16+o]);
      }
    }
    {
      const float4 x = *(const float4*)(g1buf + (size_t)slot * 4);
      #pragma unroll
      for (int c = 0; c < 16; c++) {
        const float h = sW0b[c*4+0]*x.x + sW0b[c*4+1]*x.y + sW0b[c*4+2]*x.z + sW0b[c*4+3]*x.w;
        a1[c] = fmaxf(fmaf(sP[32+c], h, sP[48+c]), 0.f);
      }
      #pragma unroll
      for (int o = 0; o < 32; o++) {
        float h2 = 0.f;
        #pragma unroll
        for (int c = 0; c < 16; c++) h2 = fmaf(sW1b[o*16+c], a1[c], h2);
        acc[32+o] += h2;
        acc[64+o]  = fmaf(h2, h2, acc[64+o]);
      }
    }
  }
  #pragma unroll
  for (int d = 1; d < 64; d <<= 1) {
    #pragma unroll
    for (int i = 0; i < 96; i++) acc[i] += __shfl_xor(acc[i], d);
  }
  const int wave = t >> 6, lane = t & 63;
  if (lane == 0) {
    for (int i = 0; i < 96; i++) lred[wave][i] = acc[i];
  }
  __syncthreads();
  if (t < 96) part1[blockIdx.x * 96 + t] = lred[0][t] + lred[1][t] + lred[2][t] + lred[3][t];
}

// ---------------------------------------------------------------------------
// K5: finalize BN1. params[64:80]=A1s0 [80:96]=B1s0 [96:128]=A1s1 [128:160]=B1s1
// ---------------------------------------------------------------------------
__global__ __launch_bounds__(128) void finalize1_kernel(
    const float* __restrict__ part1,
    const float* __restrict__ gm0, const float* __restrict__ bt0,
    const float* __restrict__ gm1, const float* __restrict__ bt1,
    float* __restrict__ params)
{
  __shared__ float S[96];
  const int t = threadIdx.x;
  if (t < 96) {
    float s = 0.f;
    for (int r = 0; r < 32; r++) s += part1[r * 96 + t];
    S[t] = s;
  }
  __syncthreads();
  if (t < 48) {
    float sum, sq, G, Bv; int oA, oB;
    if (t < 16) { sum = S[t];    sq = S[16+t]; G = gm0[t]; Bv = bt0[t]; oA = 64+t;  oB = 80+t; }
    else { const int c = t - 16; sum = S[32+c]; sq = S[64+c]; G = gm1[c]; Bv = bt1[c]; oA = 96+c; oB = 128+c; }
    const float mean = sum / MSAMP;
    const float var  = sq / MSAMP - mean * mean;
    const float A = G / sqrtf(var + 1e-5f);
    params[oA] = A;
    params[oB] = Bv - mean * A;
  }
}

// ---------------------------------------------------------------------------
// K6: MLP + max-pool per keypoint -> feats[:, 256:304].
// 16 keypoints/block, 16 slots/keypoint (one thread per slot).
// ---------------------------------------------------------------------------
__global__ __launch_bounds__(256) void pool_kernel(
    const float* __restrict__ g0buf, const float* __restrict__ g1buf,
    const int* __restrict__ cnt, const float* __restrict__ params,
    const float* __restrict__ W0s0, const float* __restrict__ W0s1,
    const float* __restrict__ W1s0, const float* __restrict__ W1s1,
    float* __restrict__ feats)
{
  __shared__ float sW0a[64], sW0b[64], sW1a[256], sW1b[512], sP[160];
  const int t = threadIdx.x;
  if (t < 64)  { sW0a[t] = W0s0[t]; sW0b[t] = W0s1[t]; }
  if (t < 160) sP[t] = params[t];
  sW1a[t]       = W1s0[t];
  sW1b[t]       = W1s1[t];
  sW1b[t + 256] = W1s1[t + 256];
  __syncthreads();

  const int lkp = t >> 4, slot = t & 15;
  const int bk = blockIdx.x * 16 + lkp;
  const size_t si = (size_t)bk * 16 + slot;
  float a1[16], a2s0[16], a2s1[32];
  {
    const float4 x = *(const float4*)(g0buf + si * 4);
    #pragma unroll
    for (int c = 0; c < 16; c++) {
      const float h = sW0a[c*4+0]*x.x + sW0a[c*4+1]*x.y + sW0a[c*4+2]*x.z + sW0a[c*4+3]*x.w;
      a1[c] = fmaxf(fmaf(sP[c], h, sP[16+c]), 0.f);
    }
    #pragma unroll
    for (int o = 0; o < 16; o++) {
      float h2 = 0.f;
      #pragma unroll
      for (int c = 0; c < 16; c++) h2 = fmaf(sW1a[o*16+c], a1[c], h2);
      a2s0[o] = fmaxf(fmaf(sP[64+o], h2, sP[80+o]), 0.f);
    }
  }
  {
    const float4 x = *(const float4*)(g1buf + si * 4);
    #pragma unroll
    for (int c = 0; c < 16; c++) {
      const float h = sW0b[c*4+0]*x.x + sW0b[c*4+1]*x.y + sW0b[c*4+2]*x.z + sW0b[c*4+3]*x.w;
      a1[c] = fmaxf(fmaf(sP[32+c], h, sP[48+c]), 0.f);
    }
    #pragma unroll
    for (int o = 0; o < 32; o++) {
      float h2 = 0.f;
      #pragma unroll
      for (int c = 0; c < 16; c++) h2 = fmaf(sW1b[o*16+c], a1[c], h2);
      a2s1[o] = fmaxf(fmaf(sP[96+o], h2, sP[128+o]), 0.f);
    }
  }
  // max over the 16 slots (16 consecutive lanes per keypoint)
  #pragma unroll
  for (int d = 1; d < 16; d <<= 1) {
    #pragma unroll
    for (int o = 0; o < 16; o++) a2s0[o] = fmaxf(a2s0[o], __shfl_xor(a2s0[o], d));
    #pragma unroll
    for (int o = 0; o < 32; o++) a2s1[o] = fmaxf(a2s1[o], __shfl_xor(a2s1[o], d));
  }
  if (slot == 0) {
    const int c0 = cnt[bk], c1 = cnt[NBK + bk];
    float* outp = feats + (size_t)bk * 304 + 256;
    #pragma unroll
    for (int o = 0; o < 16; o++) outp[o] = c0 ? a2s0[o] : 0.f;
    #pragma unroll
    for (int o = 0; o < 32; o++) outp[16 + o] = c1 ? a2s1[o] : 0.f;
  }
}

// ---------------------------------------------------------------------------
// K7: fused = feats(4096x304) @ Wf^T(304x128) + per-column partial stats.
// 16 rows per block, 128 threads = 1 column each.
// ---------------------------------------------------------------------------
__global__ __launch_bounds__(128) void fused_kernel(
    const float* __restrict__ feats, const float* __restrict__ Wf,
    float* __restrict__ fused, float* __restrict__ part2)
{
  __shared__ __align__(16) float sF[16 * 304];
  const int t = threadIdx.x;
  const int r0 = blockIdx.x * 16;
  for (int i = t; i < 16 * 304; i += 128) sF[i] = feats[(size_t)r0 * 304 + i];
  __syncthreads();
  float acc[16];
  #pragma unroll
  for (int r = 0; r < 16; r++) acc[r] = 0.f;
  const float* wrow = Wf + (size_t)t * 304;
  for (int j4 = 0; j4 < 76; j4++) {
    const float4 w = *(const float4*)(wrow + j4 * 4);
    #pragma unroll
    for (int r = 0; r < 16; r++) {
      const float4 f = *(const float4*)(sF + r * 304 + j4 * 4);
      acc[r] = fmaf(w.x, f.x, acc[r]);
      acc[r] = fmaf(w.y, f.y, acc[r]);
      acc[r] = fmaf(w.z, f.z, acc[r]);
      acc[r] = fmaf(w.w, f.w, acc[r]);
    }
  }
  float s = 0.f, q = 0.f;
  #pragma unroll
  for (int r = 0; r < 16; r++) {
    fused[(size_t)(r0 + r) * 128 + t] = acc[r];
    s += acc[r];
    q = fmaf(acc[r], acc[r], q);
  }
  part2[blockIdx.x * 256 + t]       = s;
  part2[blockIdx.x * 256 + 128 + t] = q;
}

// ---------------------------------------------------------------------------
// K8: finalize final BN. params[256:384]=Af, [384:512]=Bf
// ---------------------------------------------------------------------------
__global__ __launch_bounds__(128) void finalize2_kernel(
    const float* __restrict__ part2, const float* __restrict__ gf,
    const float* __restrict__ bfp, float* __restrict__ params)
{
  const int t = threadIdx.x;  // 0..127
  float s = 0.f, q = 0.f;
  for (int r = 0; r < 256; r++) {
    s += part2[r * 256 + t];
    q += part2[r * 256 + 128 + t];
  }
  const float mean = s / MROW;
  const float var  = q / MROW - mean * mean;
  const float A = gf[t] / sqrtf(var + 1e-5f);
  params[256 + t] = A;
  params[384 + t] = bfp[t] - mean * A;
}

// ---------------------------------------------------------------------------
// K9: apply final BN + relu (f32 output).
// ---------------------------------------------------------------------------
__global__ __launch_bounds__(256) void out_kernel(
    const float* __restrict__ fused, const float* __restrict__ params,
    float* __restrict__ out)
{
  const int i4 = blockIdx.x * 256 + threadIdx.x;   // 0..131071
  const int i = i4 * 4;
  const float4 v  = *(const float4*)(fused + i);
  const int c = i & 127;
  const float4 A  = *(const float4*)(params + 256 + c);
  const float4 Bb = *(const float4*)(params + 384 + c);
  float4 o;
  o.x = fmaxf(fmaf(v.x, A.x, Bb.x), 0.f);
  o.y = fmaxf(fmaf(v.y, A.y, Bb.y), 0.f);
  o.z = fmaxf(fmaf(v.z, A.z, Bb.z), 0.f);
  o.w = fmaxf(fmaf(v.w, A.w, Bb.w), 0.f);
  *(float4*)(out + i) = o;
}

// ---------------------------------------------------------------------------
extern "C" void kernel_launch(void* const* d_in, const int* in_sizes, int n_in,
                              void* d_out, int out_size, void* d_ws, size_t ws_size,
                              hipStream_t stream)
{
  const float* kp    = (const float*)d_in[0];
  const float* pts   = (const float*)d_in[1];
  const float* pfeat = (const float*)d_in[2];
  const float* bev   = (const float*)d_in[3];
  const int*   strd  = (const int*)d_in[4];
  const float* W0s0  = (const float*)d_in[5];
  const float* g0s0  = (const float*)d_in[6];
  const float* b0s0  = (const float*)d_in[7];
  const float* W1s0  = (const float*)d_in[8];
  const float* g1s0  = (const float*)d_in[9];
  const float* b1s0  = (const float*)d_in[10];
  const float* W0s1  = (const float*)d_in[11];
  const float* g0s1  = (const float*)d_in[12];
  const float* b0s1  = (const float*)d_in[13];
  const float* W1s1  = (const float*)d_in[14];
  const float* g1s1  = (const float*)d_in[15];
  const float* b1s1  = (const float*)d_in[16];
  const float* Wf    = (const float*)d_in[17];
  const float* gf    = (const float*)d_in[18];
  const float* bfv   = (const float*)d_in[19];

  float* w      = (float*)d_ws;
  float* g0buf  = w;                    // 262144
  float* g1buf  = w + 262144;           // 262144
  float* feats  = w + 524288;           // 4096*304 = 1245184
  float* fused  = w + 1769472;          // 4096*128 = 524288
  float* part0  = w + 2293760;          // 1024*28  = 28672
  float* part1  = w + 2322432;          // 32*96    = 3072
  float* part2  = w + 2325504;          // 256*256  = 65536
  float* params = w + 2391040;          // 512
  int*   cnt    = (int*)(w + 2391552);  // 8192 ints

  hipLaunchKernelGGL(bev_kernel,       dim3(4096), dim3(256), 0, stream, kp, bev, strd, feats);
  hipLaunchKernelGGL(group_kernel,     dim3(1024), dim3(256), 0, stream, kp, pts, pfeat, g0buf, g1buf, cnt, part0);
  hipLaunchKernelGGL(finalize0_kernel, dim3(1),    dim3(256), 0, stream, part0, W0s0, g0s0, b0s0, W0s1, g0s1, b0s1, params);
  hipLaunchKernelGGL(stats1_kernel,    dim3(32),   dim3(256), 0, stream, g0buf, g1buf, params, W0s0, W0s1, W1s0, W1s1, part1);
  hipLaunchKernelGGL(finalize1_kernel, dim3(1),    dim3(128), 0, stream, part1, g1s0, b1s0, g1s1, b1s1, params);
  hipLaunchKernelGGL(pool_kernel,      dim3(256),  dim3(256), 0, stream, g0buf, g1buf, cnt, params, W0s0, W0s1, W1s0, W1s1, feats);
  hipLaunchKernelGGL(fused_kernel,     dim3(256),  dim3(128), 0, stream, feats, Wf, fused, part2);
  hipLaunchKernelGGL(finalize2_kernel, dim3(1),    dim3(128), 0, stream, part2, gf, bfv, params);
  hipLaunchKernelGGL(out_kernel,       dim3(512),  dim3(256), 0, stream, fused, params, (float*)d_out);
}

// Round 3
// 325.989 us; speedup vs baseline: 1.6933x; 1.6933x over previous
//
#include <hip/hip_runtime.h>
#include <hip/hip_bf16.h>

#define NB    2
#define NK    2048
#define NPTS  16384
#define NBK   4096            // NB*NK
#define MSAMP 65536.0f        // NBK*16 samples per scale for BN0/BN1
#define MROW  4096.0f         // rows for final BN

// ---------------------------------------------------------------------------
// K1: BEV bilinear interpolation -> feats[:, 0:256]
// ---------------------------------------------------------------------------
__global__ __launch_bounds__(256) void bev_kernel(
    const float* __restrict__ kp, const float* __restrict__ bev,
    const int* __restrict__ stridep, float* __restrict__ feats)
{
  const int bk = blockIdx.x;           // 0..4095
  const int c  = threadIdx.x;          // channel 0..255
  const int b  = bk >> 11;
  const float st = (float)(*stridep);
  const float x = (kp[bk*3+0] - (-70.4f)) / 0.1f / st;
  const float y = (kp[bk*3+1] - (-40.0f)) / 0.1f / st;
  const int xf = (int)floorf(x), yf = (int)floorf(y);
  const int x0 = min(max(xf, 0), 175), x1 = min(max(xf + 1, 0), 175);
  const int y0 = min(max(yf, 0), 99),  y1 = min(max(yf + 1, 0), 99);
  const float x0f = (float)x0, x1f = (float)x1, y0f = (float)y0, y1f = (float)y1;
  const float wa = (x1f - x) * (y1f - y);
  const float wb = (x1f - x) * (y - y0f);
  const float wc = (x - x0f) * (y1f - y);
  const float wd = (x - x0f) * (y - y0f);
  const size_t base = ((size_t)b * 256 + c) * 17600;  // 100*176
  const float Ia = bev[base + y0 * 176 + x0];
  const float Ib = bev[base + y1 * 176 + x0];
  const float Ic = bev[base + y0 * 176 + x1];
  const float Id = bev[base + y1 * 176 + x1];
  feats[(size_t)bk * 304 + c] = Ia * wa + Ib * wb + Ic * wc + Id * wd;
}

// ---------------------------------------------------------------------------
// K2: ball query + grouping. 1 wave per keypoint, 4 waves/block.
// Writes g0,g1 (bk,slot,4) f32, cnt, and per-block BN0 moment partials:
// part0[block][28] = per-scale {Sx(4), Sxx upper-tri(10)} over the 16 slots.
// ---------------------------------------------------------------------------
__global__ __launch_bounds__(256) void group_kernel(
    const float* __restrict__ kp, const float* __restrict__ pts,
    const float* __restrict__ pfeat,
    float* __restrict__ g0buf, float* __restrict__ g1buf,
    int* __restrict__ cnt, float* __restrict__ part0)
{
  __shared__ float slots[4][2][16][4];
  __shared__ float bred[4][28];
  const int wave = threadIdx.x >> 6;
  const int lane = threadIdx.x & 63;
  const int bk = blockIdx.x * 4 + wave;
  const int b  = bk >> 11;
  const float kx = kp[bk*3+0];
  const float ky = kp[bk*3+1];
  const float kz = kp[bk*3+2];
  const float* px = pts   + (size_t)b * NPTS * 3;
  const float* pf = pfeat + (size_t)b * NPTS;
  int c0 = 0, c1 = 0;
  const unsigned long long below = (1ull << lane) - 1ull;

  for (int base = 0; base < NPTS; base += 64) {
    const int j = base + lane;
    const float x = px[j*3+0];
    const float y = px[j*3+1];
    const float z = px[j*3+2];
    const float dx = x - kx, dy = y - ky, dz = z - kz;
    const float d2 = dx*dx + dy*dy + dz*dz;
    const bool w0 = d2 < 0.16f;   // 0.4^2
    const bool w1 = d2 < 0.64f;   // 0.8^2
    const unsigned long long m1 = __ballot(w1);
    if (m1) {                      // rare (~most iterations have no hits)
      const unsigned long long m0 = __ballot(w0);
      const float f = pf[j];
      const int o0 = c0 + __popcll(m0 & below);
      if (w0 && o0 < 16) {
        slots[wave][0][o0][0] = dx; slots[wave][0][o0][1] = dy;
        slots[wave][0][o0][2] = dz; slots[wave][0][o0][3] = f;
      }
      const int o1 = c1 + __popcll(m1 & below);
      if (w1 && o1 < 16) {
        slots[wave][1][o1][0] = dx; slots[wave][1][o1][1] = dy;
        slots[wave][1][o1][2] = dz; slots[wave][1][o1][3] = f;
      }
      c0 += __popcll(m0);
      c1 += __popcll(m1);
      if (c0 >= 16) break;        // c1 >= c0 always (w0 subset of w1)
    }
  }

  // padding: empty -> zeros, partial -> replicate slot 0
  if (lane < 32) {
    const int s  = (lane >> 4) & 1;
    const int sl = lane & 15;
    const int cs = s ? c1 : c0;
    if (cs == 0) {
      slots[wave][s][sl][0] = 0.f; slots[wave][s][sl][1] = 0.f;
      slots[wave][s][sl][2] = 0.f; slots[wave][s][sl][3] = 0.f;
    } else if (sl >= cs) {
      slots[wave][s][sl][0] = slots[wave][s][0][0];
      slots[wave][s][sl][1] = slots[wave][s][0][1];
      slots[wave][s][sl][2] = slots[wave][s][0][2];
      slots[wave][s][sl][3] = slots[wave][s][0][3];
    }
  }

  // write grouped data (64 floats per scale per keypoint, coalesced)
  g0buf[(size_t)bk * 64 + lane] = slots[wave][0][lane >> 2][lane & 3];
  g1buf[(size_t)bk * 64 + lane] = slots[wave][1][lane >> 2][lane & 3];
  if (lane == 0) { cnt[bk] = c0; cnt[NBK + bk] = c1; }

  // BN0 moment partials: lanes 0..15 scale0 slots, lanes 16..31 scale1 slots
  float v[14];
  {
    float x0 = 0.f, x1 = 0.f, x2 = 0.f, x3 = 0.f;
    if (lane < 32) {
      const int s  = (lane >> 4) & 1;
      const int sl = lane & 15;
      x0 = slots[wave][s][sl][0]; x1 = slots[wave][s][sl][1];
      x2 = slots[wave][s][sl][2]; x3 = slots[wave][s][sl][3];
    }
    v[0] = x0; v[1] = x1; v[2] = x2; v[3] = x3;
    v[4] = x0*x0; v[5] = x0*x1; v[6]  = x0*x2; v[7]  = x0*x3;
    v[8] = x1*x1; v[9] = x1*x2; v[10] = x1*x3;
    v[11] = x2*x2; v[12] = x2*x3; v[13] = x3*x3;
  }
  #pragma unroll
  for (int d = 1; d < 16; d <<= 1) {
    #pragma unroll
    for (int i = 0; i < 14; i++) v[i] += __shfl_xor(v[i], d);
  }
  if (lane == 0 || lane == 16) {
    float* dst = &bred[wave][(lane >> 4) * 14];
    #pragma unroll
    for (int i = 0; i < 14; i++) dst[i] = v[i];
  }
  __syncthreads();
  if (threadIdx.x < 28) {
    const int i = threadIdx.x;
    part0[blockIdx.x * 28 + i] = bred[0][i] + bred[1][i] + bred[2][i] + bred[3][i];
  }
}

// ---------------------------------------------------------------------------
// K3: finalize BN0 (both scales) from moment partials.
// params[0:16]=A0s0 [16:32]=B0s0 [32:48]=A0s1 [48:64]=B0s1
// ---------------------------------------------------------------------------
__global__ __launch_bounds__(256) void finalize0_kernel(
    const float* __restrict__ part0,
    const float* __restrict__ W0s0, const float* __restrict__ gm0, const float* __restrict__ bt0,
    const float* __restrict__ W0s1, const float* __restrict__ gm1, const float* __restrict__ bt1,
    float* __restrict__ params)
{
  __shared__ float lred[4][28];
  __shared__ float S[28];
  const int t = threadIdx.x;
  float v[28];
  #pragma unroll
  for (int i = 0; i < 28; i++) v[i] = 0.f;
  for (int r = t; r < 1024; r += 256) {
    const float* p = part0 + r * 28;
    #pragma unroll
    for (int i = 0; i < 28; i++) v[i] += p[i];
  }
  #pragma unroll
  for (int d = 1; d < 64; d <<= 1) {
    #pragma unroll
    for (int i = 0; i < 28; i++) v[i] += __shfl_xor(v[i], d);
  }
  const int wave = t >> 6, lane = t & 63;
  if (lane == 0) {
    for (int i = 0; i < 28; i++) lred[wave][i] = v[i];
  }
  __syncthreads();
  if (t < 28) S[t] = lred[0][t] + lred[1][t] + lred[2][t] + lred[3][t];
  __syncthreads();
  if (t < 32) {
    const int s = t >> 4, c = t & 15;
    const float* W  = s ? W0s1 : W0s0;
    const float* G  = s ? gm1  : gm0;
    const float* Bt = s ? bt1  : bt0;
    const float* Sx = S + s * 14;
    const float w0 = W[c*4+0], w1 = W[c*4+1];
    const float w2 = W[c*4+2], w3 = W[c*4+3];
    const float inv = 1.0f / MSAMP;
    const float mean = (w0*Sx[0] + w1*Sx[1] + w2*Sx[2] + w3*Sx[3]) * inv;
    float e2 = w0*w0*Sx[4] + 2.f*w0*w1*Sx[5] + 2.f*w0*w2*Sx[6] + 2.f*w0*w3*Sx[7]
             + w1*w1*Sx[8] + 2.f*w1*w2*Sx[9] + 2.f*w1*w3*Sx[10]
             + w2*w2*Sx[11] + 2.f*w2*w3*Sx[12] + w3*w3*Sx[13];
    e2 *= inv;
    const float var = e2 - mean * mean;
    const float A = G[c] / sqrtf(var + 1e-5f);
    params[s*32 + c]      = A;
    params[s*32 + 16 + c] = Bt[c] - mean * A;
  }
}

// ---------------------------------------------------------------------------
// K4: second-layer BN stats, restructured: 1 slot per thread, grid 256.
// Per-channel immediate reduction: 16-lane butterfly on (h2, h2^2), sub-wave
// leaders accumulate into red[16][96]. No big register arrays, no spills.
// part1[block][96]: [0:16]=sum_s0 [16:32]=sq_s0 [32:64]=sum_s1 [64:96]=sq_s1
// ---------------------------------------------------------------------------
__global__ __launch_bounds__(256) void stats1_kernel(
    const float* __restrict__ g0buf, const float* __restrict__ g1buf,
    const float* __restrict__ params,
    const float* __restrict__ W0s0, const float* __restrict__ W0s1,
    const float* __restrict__ W1s0, const float* __restrict__ W1s1,
    float* __restrict__ part1)
{
  __shared__ float sW0a[64], sW0b[64], sW1a[256], sW1b[512], sP[64];
  __shared__ float red[16][96];
  const int t = threadIdx.x;
  if (t < 64) { sW0a[t] = W0s0[t]; sW0b[t] = W0s1[t]; sP[t] = params[t]; }
  sW1a[t]       = W1s0[t];
  sW1b[t]       = W1s1[t];
  sW1b[t + 256] = W1s1[t + 256];
  for (int i = t; i < 16 * 96; i += 256) ((float*)red)[i] = 0.f;
  __syncthreads();

  const int slot = blockIdx.x * 256 + t;        // grid 256 -> 65536 slots
  const int wave = t >> 6, lane = t & 63;
  const int grp  = (wave << 2) | (lane >> 4);   // 0..15
  const bool leader = (lane & 15) == 0;

  float a1[16];
  {  // scale 0
    const float4 x = *(const float4*)(g0buf + (size_t)slot * 4);
    #pragma unroll
    for (int c = 0; c < 16; c++) {
      const float h = sW0a[c*4+0]*x.x + sW0a[c*4+1]*x.y + sW0a[c*4+2]*x.z + sW0a[c*4+3]*x.w;
      a1[c] = fmaxf(fmaf(sP[c], h, sP[16+c]), 0.f);
    }
    #pragma unroll
    for (int o = 0; o < 16; o++) {
      float h2 = 0.f;
      #pragma unroll
      for (int c = 0; c < 16; c++) h2 = fmaf(sW1a[o*16+c], a1[c], h2);
      float s = h2, q = h2 * h2;
      #pragma unroll
      for (int d = 1; d < 16; d <<= 1) { s += __shfl_xor(s, d); q += __shfl_xor(q, d); }
      if (leader) { red[grp][o] += s; red[grp][16+o] += q; }
    }
  }
  {  // scale 1
    const float4 x = *(const float4*)(g1buf + (size_t)slot * 4);
    #pragma unroll
    for (int c = 0; c < 16; c++) {
      const float h = sW0b[c*4+0]*x.x + sW0b[c*4+1]*x.y + sW0b[c*4+2]*x.z + sW0b[c*4+3]*x.w;
      a1[c] = fmaxf(fmaf(sP[32+c], h, sP[48+c]), 0.f);
    }
    #pragma unroll
    for (int o = 0; o < 32; o++) {
      float h2 = 0.f;
      #pragma unroll
      for (int c = 0; c < 16; c++) h2 = fmaf(sW1b[o*16+c], a1[c], h2);
      float s = h2, q = h2 * h2;
      #pragma unroll
      for (int d = 1; d < 16; d <<= 1) { s += __shfl_xor(s, d); q += __shfl_xor(q, d); }
      if (leader) { red[grp][32+o] += s; red[grp][64+o] += q; }
    }
  }
  __syncthreads();
  if (t < 96) {
    float s = 0.f;
    #pragma unroll
    for (int g = 0; g < 16; g++) s += red[g][t];
    part1[blockIdx.x * 96 + t] = s;
  }
}

// ---------------------------------------------------------------------------
// K5: finalize BN1. params[64:80]=A1s0 [80:96]=B1s0 [96:128]=A1s1 [128:160]=B1s1
// ---------------------------------------------------------------------------
__global__ __launch_bounds__(128) void finalize1_kernel(
    const float* __restrict__ part1,
    const float* __restrict__ gm0, const float* __restrict__ bt0,
    const float* __restrict__ gm1, const float* __restrict__ bt1,
    float* __restrict__ params)
{
  __shared__ float S[96];
  const int t = threadIdx.x;
  if (t < 96) {
    float s0 = 0.f, s1 = 0.f, s2 = 0.f, s3 = 0.f;
    for (int r = 0; r < 256; r += 4) {
      s0 += part1[(r + 0) * 96 + t];
      s1 += part1[(r + 1) * 96 + t];
      s2 += part1[(r + 2) * 96 + t];
      s3 += part1[(r + 3) * 96 + t];
    }
    S[t] = (s0 + s1) + (s2 + s3);
  }
  __syncthreads();
  if (t < 48) {
    float sum, sq, G, Bv; int oA, oB;
    if (t < 16) { sum = S[t];    sq = S[16+t]; G = gm0[t]; Bv = bt0[t]; oA = 64+t;  oB = 80+t; }
    else { const int c = t - 16; sum = S[32+c]; sq = S[64+c]; G = gm1[c]; Bv = bt1[c]; oA = 96+c; oB = 128+c; }
    const float mean = sum / MSAMP;
    const float var  = sq / MSAMP - mean * mean;
    const float A = G / sqrtf(var + 1e-5f);
    params[oA] = A;
    params[oB] = Bv - mean * A;
  }
}

// ---------------------------------------------------------------------------
// K6: MLP + max-pool per keypoint -> feats[:, 256:304].
// 16 keypoints/block, 16 slots/keypoint (one thread per slot).
// ---------------------------------------------------------------------------
__global__ __launch_bounds__(256) void pool_kernel(
    const float* __restrict__ g0buf, const float* __restrict__ g1buf,
    const int* __restrict__ cnt, const float* __restrict__ params,
    const float* __restrict__ W0s0, const float* __restrict__ W0s1,
    const float* __restrict__ W1s0, const float* __restrict__ W1s1,
    float* __restrict__ feats)
{
  __shared__ float sW0a[64], sW0b[64], sW1a[256], sW1b[512], sP[160];
  const int t = threadIdx.x;
  if (t < 64)  { sW0a[t] = W0s0[t]; sW0b[t] = W0s1[t]; }
  if (t < 160) sP[t] = params[t];
  sW1a[t]       = W1s0[t];
  sW1b[t]       = W1s1[t];
  sW1b[t + 256] = W1s1[t + 256];
  __syncthreads();

  const int lkp = t >> 4, slot = t & 15;
  const int bk = blockIdx.x * 16 + lkp;
  const size_t si = (size_t)bk * 16 + slot;
  float a1[16], a2s0[16], a2s1[32];
  {
    const float4 x = *(const float4*)(g0buf + si * 4);
    #pragma unroll
    for (int c = 0; c < 16; c++) {
      const float h = sW0a[c*4+0]*x.x + sW0a[c*4+1]*x.y + sW0a[c*4+2]*x.z + sW0a[c*4+3]*x.w;
      a1[c] = fmaxf(fmaf(sP[c], h, sP[16+c]), 0.f);
    }
    #pragma unroll
    for (int o = 0; o < 16; o++) {
      float h2 = 0.f;
      #pragma unroll
      for (int c = 0; c < 16; c++) h2 = fmaf(sW1a[o*16+c], a1[c], h2);
      a2s0[o] = fmaxf(fmaf(sP[64+o], h2, sP[80+o]), 0.f);
    }
  }
  {
    const float4 x = *(const float4*)(g1buf + si * 4);
    #pragma unroll
    for (int c = 0; c < 16; c++) {
      const float h = sW0b[c*4+0]*x.x + sW0b[c*4+1]*x.y + sW0b[c*4+2]*x.z + sW0b[c*4+3]*x.w;
      a1[c] = fmaxf(fmaf(sP[32+c], h, sP[48+c]), 0.f);
    }
    #pragma unroll
    for (int o = 0; o < 32; o++) {
      float h2 = 0.f;
      #pragma unroll
      for (int c = 0; c < 16; c++) h2 = fmaf(sW1b[o*16+c], a1[c], h2);
      a2s1[o] = fmaxf(fmaf(sP[96+o], h2, sP[128+o]), 0.f);
    }
  }
  // max over the 16 slots (16 consecutive lanes per keypoint)
  #pragma unroll
  for (int d = 1; d < 16; d <<= 1) {
    #pragma unroll
    for (int o = 0; o < 16; o++) a2s0[o] = fmaxf(a2s0[o], __shfl_xor(a2s0[o], d));
    #pragma unroll
    for (int o = 0; o < 32; o++) a2s1[o] = fmaxf(a2s1[o], __shfl_xor(a2s1[o], d));
  }
  if (slot == 0) {
    const int c0 = cnt[bk], c1 = cnt[NBK + bk];
    float* outp = feats + (size_t)bk * 304 + 256;
    #pragma unroll
    for (int o = 0; o < 16; o++) outp[o] = c0 ? a2s0[o] : 0.f;
    #pragma unroll
    for (int o = 0; o < 32; o++) outp[16 + o] = c1 ? a2s1[o] : 0.f;
  }
}

// ---------------------------------------------------------------------------
// K7: fused = feats(4096x304) @ Wf^T(304x128) + per-column partial stats.
// 16 rows per block, 128 threads = 1 column each.
// ---------------------------------------------------------------------------
__global__ __launch_bounds__(128) void fused_kernel(
    const float* __restrict__ feats, const float* __restrict__ Wf,
    float* __restrict__ fused, float* __restrict__ part2)
{
  __shared__ __align__(16) float sF[16 * 304];
  const int t = threadIdx.x;
  const int r0 = blockIdx.x * 16;
  for (int i = t; i < 16 * 304; i += 128) sF[i] = feats[(size_t)r0 * 304 + i];
  __syncthreads();
  float acc[16];
  #pragma unroll
  for (int r = 0; r < 16; r++) acc[r] = 0.f;
  const float* wrow = Wf + (size_t)t * 304;
  for (int j4 = 0; j4 < 76; j4++) {
    const float4 w = *(const float4*)(wrow + j4 * 4);
    #pragma unroll
    for (int r = 0; r < 16; r++) {
      const float4 f = *(const float4*)(sF + r * 304 + j4 * 4);
      acc[r] = fmaf(w.x, f.x, acc[r]);
      acc[r] = fmaf(w.y, f.y, acc[r]);
      acc[r] = fmaf(w.z, f.z, acc[r]);
      acc[r] = fmaf(w.w, f.w, acc[r]);
    }
  }
  float s = 0.f, q = 0.f;
  #pragma unroll
  for (int r = 0; r < 16; r++) {
    fused[(size_t)(r0 + r) * 128 + t] = acc[r];
    s += acc[r];
    q = fmaf(acc[r], acc[r], q);
  }
  part2[blockIdx.x * 256 + t]       = s;
  part2[blockIdx.x * 256 + 128 + t] = q;
}

// ---------------------------------------------------------------------------
// K8: finalize final BN. params[256:384]=Af, [384:512]=Bf
// ---------------------------------------------------------------------------
__global__ __launch_bounds__(128) void finalize2_kernel(
    const float* __restrict__ part2, const float* __restrict__ gf,
    const float* __restrict__ bfp, float* __restrict__ params)
{
  const int t = threadIdx.x;  // 0..127
  float s = 0.f, q = 0.f;
  for (int r = 0; r < 256; r++) {
    s += part2[r * 256 + t];
    q += part2[r * 256 + 128 + t];
  }
  const float mean = s / MROW;
  const float var  = q / MROW - mean * mean;
  const float A = gf[t] / sqrtf(var + 1e-5f);
  params[256 + t] = A;
  params[384 + t] = bfp[t] - mean * A;
}

// ---------------------------------------------------------------------------
// K9: apply final BN + relu (f32 output).
// ---------------------------------------------------------------------------
__global__ __launch_bounds__(256) void out_kernel(
    const float* __restrict__ fused, const float* __restrict__ params,
    float* __restrict__ out)
{
  const int i4 = blockIdx.x * 256 + threadIdx.x;   // 0..131071
  const int i = i4 * 4;
  const float4 v  = *(const float4*)(fused + i);
  const int c = i & 127;
  const float4 A  = *(const float4*)(params + 256 + c);
  const float4 Bb = *(const float4*)(params + 384 + c);
  float4 o;
  o.x = fmaxf(fmaf(v.x, A.x, Bb.x), 0.f);
  o.y = fmaxf(fmaf(v.y, A.y, Bb.y), 0.f);
  o.z = fmaxf(fmaf(v.z, A.z, Bb.z), 0.f);
  o.w = fmaxf(fmaf(v.w, A.w, Bb.w), 0.f);
  *(float4*)(out + i) = o;
}

// ---------------------------------------------------------------------------
extern "C" void kernel_launch(void* const* d_in, const int* in_sizes, int n_in,
                              void* d_out, int out_size, void* d_ws, size_t ws_size,
                              hipStream_t stream)
{
  const float* kp    = (const float*)d_in[0];
  const float* pts   = (const float*)d_in[1];
  const float* pfeat = (const float*)d_in[2];
  const float* bev   = (const float*)d_in[3];
  const int*   strd  = (const int*)d_in[4];
  const float* W0s0  = (const float*)d_in[5];
  const float* g0s0  = (const float*)d_in[6];
  const float* b0s0  = (const float*)d_in[7];
  const float* W1s0  = (const float*)d_in[8];
  const float* g1s0  = (const float*)d_in[9];
  const float* b1s0  = (const float*)d_in[10];
  const float* W0s1  = (const float*)d_in[11];
  const float* g0s1  = (const float*)d_in[12];
  const float* b0s1  = (const float*)d_in[13];
  const float* W1s1  = (const float*)d_in[14];
  const float* g1s1  = (const float*)d_in[15];
  const float* b1s1  = (const float*)d_in[16];
  const float* Wf    = (const float*)d_in[17];
  const float* gf    = (const float*)d_in[18];
  const float* bfv   = (const float*)d_in[19];

  float* w      = (float*)d_ws;
  float* g0buf  = w;                    // 262144
  float* g1buf  = w + 262144;           // 262144
  float* feats  = w + 524288;           // 4096*304 = 1245184
  float* fused  = w + 1769472;          // 4096*128 = 524288
  float* part0  = w + 2293760;          // 1024*28  = 28672
  float* part1  = w + 2322432;          // 256*96   = 24576
  float* part2  = w + 2347008;          // 256*256  = 65536
  float* params = w + 2412544;          // 512
  int*   cnt    = (int*)(w + 2413056);  // 8192 ints

  hipLaunchKernelGGL(bev_kernel,       dim3(4096), dim3(256), 0, stream, kp, bev, strd, feats);
  hipLaunchKernelGGL(group_kernel,     dim3(1024), dim3(256), 0, stream, kp, pts, pfeat, g0buf, g1buf, cnt, part0);
  hipLaunchKernelGGL(finalize0_kernel, dim3(1),    dim3(256), 0, stream, part0, W0s0, g0s0, b0s0, W0s1, g0s1, b0s1, params);
  hipLaunchKernelGGL(stats1_kernel,    dim3(256),  dim3(256), 0, stream, g0buf, g1buf, params, W0s0, W0s1, W1s0, W1s1, part1);
  hipLaunchKernelGGL(finalize1_kernel, dim3(1),    dim3(128), 0, stream, part1, g1s0, b1s0, g1s1, b1s1, params);
  hipLaunchKernelGGL(pool_kernel,      dim3(256),  dim3(256), 0, stream, g0buf, g1buf, cnt, params, W0s0, W0s1, W1s0, W1s1, feats);
  hipLaunchKernelGGL(fused_kernel,     dim3(256),  dim3(128), 0, stream, feats, Wf, fused, part2);
  hipLaunchKernelGGL(finalize2_kernel, dim3(1),    dim3(128), 0, stream, part2, gf, bfv, params);
  hipLaunchKernelGGL(out_kernel,       dim3(512),  dim3(256), 0, stream, fused, params, (float*)d_out);
}

// Round 4
// 247.591 us; speedup vs baseline: 2.2295x; 1.3166x over previous
//
#include <hip/hip_runtime.h>
#include <hip/hip_bf16.h>

#define NB    2
#define NK    2048
#define NPTS  16384
#define NBK   4096            // NB*NK
#define MSAMP 65536.0f        // NBK*16 samples per scale for BN0/BN1
#define MROW  4096.0f         // rows for final BN

// ---------------------------------------------------------------------------
// K1: BEV bilinear interpolation -> feats[:, 0:256]
// ---------------------------------------------------------------------------
__global__ __launch_bounds__(256) void bev_kernel(
    const float* __restrict__ kp, const float* __restrict__ bev,
    const int* __restrict__ stridep, float* __restrict__ feats)
{
  const int bk = blockIdx.x;           // 0..4095
  const int c  = threadIdx.x;          // channel 0..255
  const int b  = bk >> 11;
  const float st = (float)(*stridep);
  const float x = (kp[bk*3+0] - (-70.4f)) / 0.1f / st;
  const float y = (kp[bk*3+1] - (-40.0f)) / 0.1f / st;
  const int xf = (int)floorf(x), yf = (int)floorf(y);
  const int x0 = min(max(xf, 0), 175), x1 = min(max(xf + 1, 0), 175);
  const int y0 = min(max(yf, 0), 99),  y1 = min(max(yf + 1, 0), 99);
  const float x0f = (float)x0, x1f = (float)x1, y0f = (float)y0, y1f = (float)y1;
  const float wa = (x1f - x) * (y1f - y);
  const float wb = (x1f - x) * (y - y0f);
  const float wc = (x - x0f) * (y1f - y);
  const float wd = (x - x0f) * (y - y0f);
  const size_t base = ((size_t)b * 256 + c) * 17600;  // 100*176
  const float Ia = bev[base + y0 * 176 + x0];
  const float Ib = bev[base + y1 * 176 + x0];
  const float Ic = bev[base + y0 * 176 + x1];
  const float Id = bev[base + y1 * 176 + x1];
  feats[(size_t)bk * 304 + c] = Ia * wa + Ib * wb + Ic * wc + Id * wd;
}

// ---------------------------------------------------------------------------
// K2: ball query + grouping, LDS-tiled. 1 wave per keypoint, 4 waves/block.
// Block stages 1024-point tiles (xyz via float4, feat) into LDS; each wave
// scans the tile from LDS (no global latency in hot loop). Compaction
// semantics identical to the verified r2 version.
// ---------------------------------------------------------------------------
__global__ __launch_bounds__(256) void group_kernel(
    const float* __restrict__ kp, const float* __restrict__ pts,
    const float* __restrict__ pfeat,
    float* __restrict__ g0buf, float* __restrict__ g1buf,
    int* __restrict__ cnt, float* __restrict__ part0)
{
  __shared__ float sxyz[3072];          // 1024 points * 3 (point-major)
  __shared__ float sfeat[1024];
  __shared__ float slots[4][2][16][4];
  __shared__ float bred[4][28];
  const int t = threadIdx.x;
  const int wave = t >> 6;
  const int lane = t & 63;
  const int bk = blockIdx.x * 4 + wave;
  const int b  = blockIdx.x >> 9;       // 512 blocks per batch
  const float kx = kp[bk*3+0];
  const float ky = kp[bk*3+1];
  const float kz = kp[bk*3+2];
  const float* px = pts   + (size_t)b * NPTS * 3;
  const float* pf = pfeat + (size_t)b * NPTS;
  int c0 = 0, c1 = 0;
  bool done = false;
  const unsigned long long below = (1ull << lane) - 1ull;

  for (int tile = 0; tile < 16; tile++) {
    __syncthreads();                    // protect LDS from previous tile's readers
    // stage 1024 points: 3072 floats = 768 float4 (3 per thread) + 1024 feats
    {
      const float4* gsrc = (const float4*)(px + tile * 3072);
      float4* ldst = (float4*)sxyz;
      ldst[t]       = gsrc[t];
      ldst[t + 256] = gsrc[t + 256];
      ldst[t + 512] = gsrc[t + 512];
      #pragma unroll
      for (int i = 0; i < 4; i++) sfeat[t + i * 256] = pf[tile * 1024 + t + i * 256];
    }
    __syncthreads();
    if (!done) {
      for (int inner = 0; inner < 16; inner++) {
        const int pp = inner * 64 + lane;
        const float x = sxyz[pp*3+0];
        const float y = sxyz[pp*3+1];
        const float z = sxyz[pp*3+2];
        const float dx = x - kx, dy = y - ky, dz = z - kz;
        const float d2 = dx*dx + dy*dy + dz*dz;
        const bool w0 = d2 < 0.16f;   // 0.4^2
        const bool w1 = d2 < 0.64f;   // 0.8^2
        const unsigned long long m1 = __ballot(w1);
        if (m1) {                      // rare
          const unsigned long long m0 = __ballot(w0);
          const float f = sfeat[pp];
          const int o0 = c0 + __popcll(m0 & below);
          if (w0 && o0 < 16) {
            slots[wave][0][o0][0] = dx; slots[wave][0][o0][1] = dy;
            slots[wave][0][o0][2] = dz; slots[wave][0][o0][3] = f;
          }
          const int o1 = c1 + __popcll(m1 & below);
          if (w1 && o1 < 16) {
            slots[wave][1][o1][0] = dx; slots[wave][1][o1][1] = dy;
            slots[wave][1][o1][2] = dz; slots[wave][1][o1][3] = f;
          }
          c0 += __popcll(m0);
          c1 += __popcll(m1);
          if (c0 >= 16) { done = true; break; }  // c1 >= c0 always
        }
      }
    }
  }
  __syncthreads();

  // padding: empty -> zeros, partial -> replicate slot 0
  if (lane < 32) {
    const int s  = (lane >> 4) & 1;
    const int sl = lane & 15;
    const int cs = s ? c1 : c0;
    if (cs == 0) {
      slots[wave][s][sl][0] = 0.f; slots[wave][s][sl][1] = 0.f;
      slots[wave][s][sl][2] = 0.f; slots[wave][s][sl][3] = 0.f;
    } else if (sl >= cs) {
      slots[wave][s][sl][0] = slots[wave][s][0][0];
      slots[wave][s][sl][1] = slots[wave][s][0][1];
      slots[wave][s][sl][2] = slots[wave][s][0][2];
      slots[wave][s][sl][3] = slots[wave][s][0][3];
    }
  }

  // write grouped data (64 floats per scale per keypoint, coalesced)
  g0buf[(size_t)bk * 64 + lane] = slots[wave][0][lane >> 2][lane & 3];
  g1buf[(size_t)bk * 64 + lane] = slots[wave][1][lane >> 2][lane & 3];
  if (lane == 0) { cnt[bk] = c0; cnt[NBK + bk] = c1; }

  // BN0 moment partials: lanes 0..15 scale0 slots, lanes 16..31 scale1 slots
  float v[14];
  {
    float x0 = 0.f, x1 = 0.f, x2 = 0.f, x3 = 0.f;
    if (lane < 32) {
      const int s  = (lane >> 4) & 1;
      const int sl = lane & 15;
      x0 = slots[wave][s][sl][0]; x1 = slots[wave][s][sl][1];
      x2 = slots[wave][s][sl][2]; x3 = slots[wave][s][sl][3];
    }
    v[0] = x0; v[1] = x1; v[2] = x2; v[3] = x3;
    v[4] = x0*x0; v[5] = x0*x1; v[6]  = x0*x2; v[7]  = x0*x3;
    v[8] = x1*x1; v[9] = x1*x2; v[10] = x1*x3;
    v[11] = x2*x2; v[12] = x2*x3; v[13] = x3*x3;
  }
  #pragma unroll
  for (int d = 1; d < 16; d <<= 1) {
    #pragma unroll
    for (int i = 0; i < 14; i++) v[i] += __shfl_xor(v[i], d);
  }
  if (lane == 0 || lane == 16) {
    float* dst = &bred[wave][(lane >> 4) * 14];
    #pragma unroll
    for (int i = 0; i < 14; i++) dst[i] = v[i];
  }
  __syncthreads();
  if (t < 28) {
    part0[blockIdx.x * 28 + t] = bred[0][t] + bred[1][t] + bred[2][t] + bred[3][t];
  }
}

// ---------------------------------------------------------------------------
// K3: finalize BN0 (both scales) from moment partials.
// params[0:16]=A0s0 [16:32]=B0s0 [32:48]=A0s1 [48:64]=B0s1
// ---------------------------------------------------------------------------
__global__ __launch_bounds__(256) void finalize0_kernel(
    const float* __restrict__ part0,
    const float* __restrict__ W0s0, const float* __restrict__ gm0, const float* __restrict__ bt0,
    const float* __restrict__ W0s1, const float* __restrict__ gm1, const float* __restrict__ bt1,
    float* __restrict__ params)
{
  __shared__ float lred[4][28];
  __shared__ float S[28];
  const int t = threadIdx.x;
  float v[28];
  #pragma unroll
  for (int i = 0; i < 28; i++) v[i] = 0.f;
  for (int r = t; r < 1024; r += 256) {
    const float* p = part0 + r * 28;
    #pragma unroll
    for (int i = 0; i < 28; i++) v[i] += p[i];
  }
  #pragma unroll
  for (int d = 1; d < 64; d <<= 1) {
    #pragma unroll
    for (int i = 0; i < 28; i++) v[i] += __shfl_xor(v[i], d);
  }
  const int wave = t >> 6, lane = t & 63;
  if (lane == 0) {
    for (int i = 0; i < 28; i++) lred[wave][i] = v[i];
  }
  __syncthreads();
  if (t < 28) S[t] = lred[0][t] + lred[1][t] + lred[2][t] + lred[3][t];
  __syncthreads();
  if (t < 32) {
    const int s = t >> 4, c = t & 15;
    const float* W  = s ? W0s1 : W0s0;
    const float* G  = s ? gm1  : gm0;
    const float* Bt = s ? bt1  : bt0;
    const float* Sx = S + s * 14;
    const float w0 = W[c*4+0], w1 = W[c*4+1];
    const float w2 = W[c*4+2], w3 = W[c*4+3];
    const float inv = 1.0f / MSAMP;
    const float mean = (w0*Sx[0] + w1*Sx[1] + w2*Sx[2] + w3*Sx[3]) * inv;
    float e2 = w0*w0*Sx[4] + 2.f*w0*w1*Sx[5] + 2.f*w0*w2*Sx[6] + 2.f*w0*w3*Sx[7]
             + w1*w1*Sx[8] + 2.f*w1*w2*Sx[9] + 2.f*w1*w3*Sx[10]
             + w2*w2*Sx[11] + 2.f*w2*w3*Sx[12] + w3*w3*Sx[13];
    e2 *= inv;
    const float var = e2 - mean * mean;
    const float A = G[c] / sqrtf(var + 1e-5f);
    params[s*32 + c]      = A;
    params[s*32 + 16 + c] = Bt[c] - mean * A;
  }
}

// ---------------------------------------------------------------------------
// K4: second-layer BN stats: 1 slot per thread, grid 256.
// part1[block][96]: [0:16]=sum_s0 [16:32]=sq_s0 [32:64]=sum_s1 [64:96]=sq_s1
// ---------------------------------------------------------------------------
__global__ __launch_bounds__(256) void stats1_kernel(
    const float* __restrict__ g0buf, const float* __restrict__ g1buf,
    const float* __restrict__ params,
    const float* __restrict__ W0s0, const float* __restrict__ W0s1,
    const float* __restrict__ W1s0, const float* __restrict__ W1s1,
    float* __restrict__ part1)
{
  __shared__ float sW0a[64], sW0b[64], sW1a[256], sW1b[512], sP[64];
  __shared__ float red[16][96];
  const int t = threadIdx.x;
  if (t < 64) { sW0a[t] = W0s0[t]; sW0b[t] = W0s1[t]; sP[t] = params[t]; }
  sW1a[t]       = W1s0[t];
  sW1b[t]       = W1s1[t];
  sW1b[t + 256] = W1s1[t + 256];
  for (int i = t; i < 16 * 96; i += 256) ((float*)red)[i] = 0.f;
  __syncthreads();

  const int slot = blockIdx.x * 256 + t;        // grid 256 -> 65536 slots
  const int wave = t >> 6, lane = t & 63;
  const int grp  = (wave << 2) | (lane >> 4);   // 0..15
  const bool leader = (lane & 15) == 0;

  float a1[16];
  {  // scale 0
    const float4 x = *(const float4*)(g0buf + (size_t)slot * 4);
    #pragma unroll
    for (int c = 0; c < 16; c++) {
      const float h = sW0a[c*4+0]*x.x + sW0a[c*4+1]*x.y + sW0a[c*4+2]*x.z + sW0a[c*4+3]*x.w;
      a1[c] = fmaxf(fmaf(sP[c], h, sP[16+c]), 0.f);
    }
    #pragma unroll
    for (int o = 0; o < 16; o++) {
      float h2 = 0.f;
      #pragma unroll
      for (int c = 0; c < 16; c++) h2 = fmaf(sW1a[o*16+c], a1[c], h2);
      float s = h2, q = h2 * h2;
      #pragma unroll
      for (int d = 1; d < 16; d <<= 1) { s += __shfl_xor(s, d); q += __shfl_xor(q, d); }
      if (leader) { red[grp][o] += s; red[grp][16+o] += q; }
    }
  }
  {  // scale 1
    const float4 x = *(const float4*)(g1buf + (size_t)slot * 4);
    #pragma unroll
    for (int c = 0; c < 16; c++) {
      const float h = sW0b[c*4+0]*x.x + sW0b[c*4+1]*x.y + sW0b[c*4+2]*x.z + sW0b[c*4+3]*x.w;
      a1[c] = fmaxf(fmaf(sP[32+c], h, sP[48+c]), 0.f);
    }
    #pragma unroll
    for (int o = 0; o < 32; o++) {
      float h2 = 0.f;
      #pragma unroll
      for (int c = 0; c < 16; c++) h2 = fmaf(sW1b[o*16+c], a1[c], h2);
      float s = h2, q = h2 * h2;
      #pragma unroll
      for (int d = 1; d < 16; d <<= 1) { s += __shfl_xor(s, d); q += __shfl_xor(q, d); }
      if (leader) { red[grp][32+o] += s; red[grp][64+o] += q; }
    }
  }
  __syncthreads();
  if (t < 96) {
    float s = 0.f;
    #pragma unroll
    for (int g = 0; g < 16; g++) s += red[g][t];
    part1[blockIdx.x * 96 + t] = s;
  }
}

// ---------------------------------------------------------------------------
// K5: finalize BN1. params[64:80]=A1s0 [80:96]=B1s0 [96:128]=A1s1 [128:160]=B1s1
// ---------------------------------------------------------------------------
__global__ __launch_bounds__(128) void finalize1_kernel(
    const float* __restrict__ part1,
    const float* __restrict__ gm0, const float* __restrict__ bt0,
    const float* __restrict__ gm1, const float* __restrict__ bt1,
    float* __restrict__ params)
{
  __shared__ float S[96];
  const int t = threadIdx.x;
  if (t < 96) {
    float s0 = 0.f, s1 = 0.f, s2 = 0.f, s3 = 0.f;
    for (int r = 0; r < 256; r += 4) {
      s0 += part1[(r + 0) * 96 + t];
      s1 += part1[(r + 1) * 96 + t];
      s2 += part1[(r + 2) * 96 + t];
      s3 += part1[(r + 3) * 96 + t];
    }
    S[t] = (s0 + s1) + (s2 + s3);
  }
  __syncthreads();
  if (t < 48) {
    float sum, sq, G, Bv; int oA, oB;
    if (t < 16) { sum = S[t];    sq = S[16+t]; G = gm0[t]; Bv = bt0[t]; oA = 64+t;  oB = 80+t; }
    else { const int c = t - 16; sum = S[32+c]; sq = S[64+c]; G = gm1[c]; Bv = bt1[c]; oA = 96+c; oB = 128+c; }
    const float mean = sum / MSAMP;
    const float var  = sq / MSAMP - mean * mean;
    const float A = G / sqrtf(var + 1e-5f);
    params[oA] = A;
    params[oB] = Bv - mean * A;
  }
}

// ---------------------------------------------------------------------------
// K6: MLP + max-pool per keypoint -> feats[:, 256:304].
// 16 keypoints/block, 16 slots/keypoint (one thread per slot).
// ---------------------------------------------------------------------------
__global__ __launch_bounds__(256) void pool_kernel(
    const float* __restrict__ g0buf, const float* __restrict__ g1buf,
    const int* __restrict__ cnt, const float* __restrict__ params,
    const float* __restrict__ W0s0, const float* __restrict__ W0s1,
    const float* __restrict__ W1s0, const float* __restrict__ W1s1,
    float* __restrict__ feats)
{
  __shared__ float sW0a[64], sW0b[64], sW1a[256], sW1b[512], sP[160];
  const int t = threadIdx.x;
  if (t < 64)  { sW0a[t] = W0s0[t]; sW0b[t] = W0s1[t]; }
  if (t < 160) sP[t] = params[t];
  sW1a[t]       = W1s0[t];
  sW1b[t]       = W1s1[t];
  sW1b[t + 256] = W1s1[t + 256];
  __syncthreads();

  const int lkp = t >> 4, slot = t & 15;
  const int bk = blockIdx.x * 16 + lkp;
  const size_t si = (size_t)bk * 16 + slot;
  float a1[16], a2s0[16], a2s1[32];
  {
    const float4 x = *(const float4*)(g0buf + si * 4);
    #pragma unroll
    for (int c = 0; c < 16; c++) {
      const float h = sW0a[c*4+0]*x.x + sW0a[c*4+1]*x.y + sW0a[c*4+2]*x.z + sW0a[c*4+3]*x.w;
      a1[c] = fmaxf(fmaf(sP[c], h, sP[16+c]), 0.f);
    }
    #pragma unroll
    for (int o = 0; o < 16; o++) {
      float h2 = 0.f;
      #pragma unroll
      for (int c = 0; c < 16; c++) h2 = fmaf(sW1a[o*16+c], a1[c], h2);
      a2s0[o] = fmaxf(fmaf(sP[64+o], h2, sP[80+o]), 0.f);
    }
  }
  {
    const float4 x = *(const float4*)(g1buf + si * 4);
    #pragma unroll
    for (int c = 0; c < 16; c++) {
      const float h = sW0b[c*4+0]*x.x + sW0b[c*4+1]*x.y + sW0b[c*4+2]*x.z + sW0b[c*4+3]*x.w;
      a1[c] = fmaxf(fmaf(sP[32+c], h, sP[48+c]), 0.f);
    }
    #pragma unroll
    for (int o = 0; o < 32; o++) {
      float h2 = 0.f;
      #pragma unroll
      for (int c = 0; c < 16; c++) h2 = fmaf(sW1b[o*16+c], a1[c], h2);
      a2s1[o] = fmaxf(fmaf(sP[96+o], h2, sP[128+o]), 0.f);
    }
  }
  // max over the 16 slots (16 consecutive lanes per keypoint)
  #pragma unroll
  for (int d = 1; d < 16; d <<= 1) {
    #pragma unroll
    for (int o = 0; o < 16; o++) a2s0[o] = fmaxf(a2s0[o], __shfl_xor(a2s0[o], d));
    #pragma unroll
    for (int o = 0; o < 32; o++) a2s1[o] = fmaxf(a2s1[o], __shfl_xor(a2s1[o], d));
  }
  if (slot == 0) {
    const int c0 = cnt[bk], c1 = cnt[NBK + bk];
    float* outp = feats + (size_t)bk * 304 + 256;
    #pragma unroll
    for (int o = 0; o < 16; o++) outp[o] = c0 ? a2s0[o] : 0.f;
    #pragma unroll
    for (int o = 0; o < 32; o++) outp[16 + o] = c1 ? a2s1[o] : 0.f;
  }
}

// ---------------------------------------------------------------------------
// K7: fused = feats(4096x304) @ Wf^T(304x128) + per-column partial stats.
// 16 rows per block, 128 threads = 1 column each.
// ---------------------------------------------------------------------------
__global__ __launch_bounds__(128) void fused_kernel(
    const float* __restrict__ feats, const float* __restrict__ Wf,
    float* __restrict__ fused, float* __restrict__ part2)
{
  __shared__ __align__(16) float sF[16 * 304];
  const int t = threadIdx.x;
  const int r0 = blockIdx.x * 16;
  for (int i = t; i < 16 * 304; i += 128) sF[i] = feats[(size_t)r0 * 304 + i];
  __syncthreads();
  float acc[16];
  #pragma unroll
  for (int r = 0; r < 16; r++) acc[r] = 0.f;
  const float* wrow = Wf + (size_t)t * 304;
  for (int j4 = 0; j4 < 76; j4++) {
    const float4 w = *(const float4*)(wrow + j4 * 4);
    #pragma unroll
    for (int r = 0; r < 16; r++) {
      const float4 f = *(const float4*)(sF + r * 304 + j4 * 4);
      acc[r] = fmaf(w.x, f.x, acc[r]);
      acc[r] = fmaf(w.y, f.y, acc[r]);
      acc[r] = fmaf(w.z, f.z, acc[r]);
      acc[r] = fmaf(w.w, f.w, acc[r]);
    }
  }
  float s = 0.f, q = 0.f;
  #pragma unroll
  for (int r = 0; r < 16; r++) {
    fused[(size_t)(r0 + r) * 128 + t] = acc[r];
    s += acc[r];
    q = fmaf(acc[r], acc[r], q);
  }
  part2[blockIdx.x * 256 + t]       = s;
  part2[blockIdx.x * 256 + 128 + t] = q;
}

// ---------------------------------------------------------------------------
// K8: finalize final BN. params[256:384]=Af, [384:512]=Bf
// ---------------------------------------------------------------------------
__global__ __launch_bounds__(128) void finalize2_kernel(
    const float* __restrict__ part2, const float* __restrict__ gf,
    const float* __restrict__ bfp, float* __restrict__ params)
{
  const int t = threadIdx.x;  // 0..127
  float s = 0.f, q = 0.f;
  for (int r = 0; r < 256; r++) {
    s += part2[r * 256 + t];
    q += part2[r * 256 + 128 + t];
  }
  const float mean = s / MROW;
  const float var  = q / MROW - mean * mean;
  const float A = gf[t] / sqrtf(var + 1e-5f);
  params[256 + t] = A;
  params[384 + t] = bfp[t] - mean * A;
}

// ---------------------------------------------------------------------------
// K9: apply final BN + relu (f32 output).
// ---------------------------------------------------------------------------
__global__ __launch_bounds__(256) void out_kernel(
    const float* __restrict__ fused, const float* __restrict__ params,
    float* __restrict__ out)
{
  const int i4 = blockIdx.x * 256 + threadIdx.x;   // 0..131071
  const int i = i4 * 4;
  const float4 v  = *(const float4*)(fused + i);
  const int c = i & 127;
  const float4 A  = *(const float4*)(params + 256 + c);
  const float4 Bb = *(const float4*)(params + 384 + c);
  float4 o;
  o.x = fmaxf(fmaf(v.x, A.x, Bb.x), 0.f);
  o.y = fmaxf(fmaf(v.y, A.y, Bb.y), 0.f);
  o.z = fmaxf(fmaf(v.z, A.z, Bb.z), 0.f);
  o.w = fmaxf(fmaf(v.w, A.w, Bb.w), 0.f);
  *(float4*)(out + i) = o;
}

// ---------------------------------------------------------------------------
extern "C" void kernel_launch(void* const* d_in, const int* in_sizes, int n_in,
                              void* d_out, int out_size, void* d_ws, size_t ws_size,
                              hipStream_t stream)
{
  const float* kp    = (const float*)d_in[0];
  const float* pts   = (const float*)d_in[1];
  const float* pfeat = (const float*)d_in[2];
  const float* bev   = (const float*)d_in[3];
  const int*   strd  = (const int*)d_in[4];
  const float* W0s0  = (const float*)d_in[5];
  const float* g0s0  = (const float*)d_in[6];
  const float* b0s0  = (const float*)d_in[7];
  const float* W1s0  = (const float*)d_in[8];
  const float* g1s0  = (const float*)d_in[9];
  const float* b1s0  = (const float*)d_in[10];
  const float* W0s1  = (const float*)d_in[11];
  const float* g0s1  = (const float*)d_in[12];
  const float* b0s1  = (const float*)d_in[13];
  const float* W1s1  = (const float*)d_in[14];
  const float* g1s1  = (const float*)d_in[15];
  const float* b1s1  = (const float*)d_in[16];
  const float* Wf    = (const float*)d_in[17];
  const float* gf    = (const float*)d_in[18];
  const float* bfv   = (const float*)d_in[19];

  float* w      = (float*)d_ws;
  float* g0buf  = w;                    // 262144
  float* g1buf  = w + 262144;           // 262144
  float* feats  = w + 524288;           // 4096*304 = 1245184
  float* fused  = w + 1769472;          // 4096*128 = 524288
  float* part0  = w + 2293760;          // 1024*28  = 28672
  float* part1  = w + 2322432;          // 256*96   = 24576
  float* part2  = w + 2347008;          // 256*256  = 65536
  float* params = w + 2412544;          // 512
  int*   cnt    = (int*)(w + 2413056);  // 8192 ints

  hipLaunchKernelGGL(bev_kernel,       dim3(4096), dim3(256), 0, stream, kp, bev, strd, feats);
  hipLaunchKernelGGL(group_kernel,     dim3(1024), dim3(256), 0, stream, kp, pts, pfeat, g0buf, g1buf, cnt, part0);
  hipLaunchKernelGGL(finalize0_kernel, dim3(1),    dim3(256), 0, stream, part0, W0s0, g0s0, b0s0, W0s1, g0s1, b0s1, params);
  hipLaunchKernelGGL(stats1_kernel,    dim3(256),  dim3(256), 0, stream, g0buf, g1buf, params, W0s0, W0s1, W1s0, W1s1, part1);
  hipLaunchKernelGGL(finalize1_kernel, dim3(1),    dim3(128), 0, stream, part1, g1s0, b1s0, g1s1, b1s1, params);
  hipLaunchKernelGGL(pool_kernel,      dim3(256),  dim3(256), 0, stream, g0buf, g1buf, cnt, params, W0s0, W0s1, W1s0, W1s1, feats);
  hipLaunchKernelGGL(fused_kernel,     dim3(256),  dim3(128), 0, stream, feats, Wf, fused, part2);
  hipLaunchKernelGGL(finalize2_kernel, dim3(1),    dim3(128), 0, stream, part2, gf, bfv, params);
  hipLaunchKernelGGL(out_kernel,       dim3(512),  dim3(256), 0, stream, fused, params, (float*)d_out);
}